// Round 12
// baseline (142.843 us; speedup 1.0000x reference)
//
#include <hip/hip_runtime.h>

// Causal MHA: B=2, H=16, S=2048, DH=64. fp32 in/out. bf16 MFMA inside.
// R21: SINGLE-PASS, COMBINE ELIMINATED. Causal geometry gift: per bh the 16
// q-pair items have k-lengths 2,4,...,32 tiles, which pair exactly into 8
// pairs of 34 tiles: (32,2),(30,4),... -> 256 blocks (one per CU), each with
// an IDENTICAL deterministic 34-tile workload. Each item runs its full
// k-range, normalizes in-kernel, writes O directly: split-k, pO/pL (58MB of
// partial round-trip), and the combine dispatch all deleted. Balance is
// exact by construction -- no scheduler assumptions (R16 lesson). Residency
// 1 block/CU = 8 waves (25%): de-risked by R17 (24% occ == 35% occ perf).
// Per-item machinery byte-identical to R20: 512 thr, 8 waves = (kh, qh0..3),
// 32x32 quadrant St (K read once/wave), in-register P via hi-half swap
// (pst never exists), VALU l, K+V double-buffer, 1 barrier/tile, causal
// tile-skip (diag_kt wave-uniform), LDS-overlay epilogue reduction.
// Item-boundary barrier protects epilogue fs reads vs next item's staging.
// prep (bf16 Q*0.125*log2e, K, V^T dword-swizzled) and fallbacks unchanged.

#define S_LEN  2048
#define DHDIM  64
#define NHEADS 32   // B*H
#define LDP    72   // padded LDS row length in shorts (144B = 9*16B)
#define M2     23.083120654223414f   // 16 * log2(e)
#define QSCALE 0.18033688011117658f  // 0.125 * log2(e)

typedef __attribute__((ext_vector_type(8))) short bf16x8;
typedef __attribute__((ext_vector_type(4))) float f32x4;
typedef __attribute__((ext_vector_type(16))) float f32x16;

__device__ __forceinline__ float fast_exp2(float x) {
#if __has_builtin(__builtin_amdgcn_exp2f)
    return __builtin_amdgcn_exp2f(x);
#else
    return exp2f(x);
#endif
}
__device__ __forceinline__ unsigned short f2bf(float f) { // RNE
    unsigned u = __float_as_uint(f);
    return (unsigned short)((u + 0x7fffu + ((u >> 16) & 1u)) >> 16);
}
__device__ __forceinline__ void ld8(const float* p, float* f) {
    float4 a = *(const float4*)p, b = *(const float4*)(p + 4);
    f[0]=a.x; f[1]=a.y; f[2]=a.z; f[3]=a.w; f[4]=b.x; f[5]=b.y; f[6]=b.z; f[7]=b.w;
}
__device__ __forceinline__ uint4 pack8(const float* f, float scale) {
    union { uint4 v; unsigned short s[8]; } w;
    #pragma unroll
    for (int j = 0; j < 8; j++) w.s[j] = f2bf(f[j] * scale);
    return w.v;
}
// combine high-16s of two floats into one dword: [lo16=a.hi16, hi16=b.hi16]
__device__ __forceinline__ unsigned packhi(float a, float b) {
#if __has_builtin(__builtin_amdgcn_perm)
    return __builtin_amdgcn_perm(__float_as_uint(b), __float_as_uint(a), 0x07060302u);
#else
    return (__float_as_uint(a) >> 16) | (__float_as_uint(b) & 0xffff0000u);
#endif
}
__device__ __forceinline__ bf16x8 mk_bf16x8(unsigned d0, unsigned d1,
                                            unsigned d2, unsigned d3) {
    union { unsigned u[4]; bf16x8 v; } w;
    w.u[0] = d0; w.u[1] = d1; w.u[2] = d2; w.u[3] = d3;
    return w.v;
}

// ---- pre-pass: per block (st, bh): V 64x64 tile -> bf16 V^T tile, plus a
// 4096-elem chunk of Q (scaled) and K -> bf16.
__global__ __launch_bounds__(256) void prep(
    const float* __restrict__ Qf, const float* __restrict__ Kf,
    const float* __restrict__ Vf, unsigned short* __restrict__ qb,
    unsigned short* __restrict__ kb, unsigned short* __restrict__ vtb)
{
    const int st = blockIdx.x, bh = blockIdx.y;
    __shared__ unsigned lt32[64][LDP / 2];   // dword view: 36 dwords/row
    const float* vp = Vf + ((size_t)bh * S_LEN + st * 64) * DHDIM;
    {
        const int c = threadIdx.x;
        const int sp = c >> 3;            // s-pair index 0..31
        const int d0 = (c & 7) * 8;
        float fa[8], fb[8];
        ld8(vp + (2 * sp) * DHDIM + d0, fa);
        ld8(vp + (2 * sp + 1) * DHDIM + d0, fb);
        #pragma unroll
        for (int j = 0; j < 8; j++) {
            int d = d0 + j;
            int colw = (sp & 3) | ((((sp >> 2) ^ (d >> 3)) & 7) << 2);
            lt32[d][colw] = (unsigned)f2bf(fa[j]) | ((unsigned)f2bf(fb[j]) << 16);
        }
    }
    size_t off = ((size_t)(bh * 32 + st) * 4096) + (size_t)threadIdx.x * 16;
    float f[8];
    ld8(Qf + off, f);     *(uint4*)(qb + off)     = pack8(f, QSCALE);
    ld8(Qf + off + 8, f); *(uint4*)(qb + off + 8) = pack8(f, QSCALE);
    ld8(Kf + off, f);     *(uint4*)(kb + off)     = pack8(f, 1.0f);
    ld8(Kf + off + 8, f); *(uint4*)(kb + off + 8) = pack8(f, 1.0f);
    __syncthreads();
    unsigned short* op = vtb + (size_t)bh * DHDIM * S_LEN + st * 64;
    for (int c = threadIdx.x; c < 512; c += 256) {
        int d = c >> 3, q = c & 7;
        int colw = ((q ^ (d >> 3)) & 7) << 2;
        *(uint4*)(op + (size_t)d * S_LEN + q * 8) = *(const uint4*)&lt32[d][colw];
    }
}

// ---- main: 256 blocks (1/CU), 512 thr, 8 waves = (kh, qh 0..3).
// Block b = bh*8 + i8 processes items qp = 15-i8 then qp = i8 sequentially:
// deterministic 34 staged tiles per block. Whole-range items, direct O.
__global__ __launch_bounds__(512) void fattn_single(
    const unsigned short* __restrict__ Qp, const unsigned short* __restrict__ Kp,
    const unsigned short* __restrict__ Vp, float* __restrict__ O)
{
    __shared__ unsigned short smem[256 * LDP]; // ksA | ksB | vtsA | vtsB (36.9KB)
    unsigned short (*ksA)[LDP]  = (unsigned short(*)[LDP])smem;
    unsigned short (*ksB)[LDP]  = (unsigned short(*)[LDP])(smem + 64 * LDP);
    unsigned short (*vtsA)[LDP] = (unsigned short(*)[LDP])(smem + 128 * LDP);
    unsigned short (*vtsB)[LDP] = (unsigned short(*)[LDP])(smem + 192 * LDP);

    const int b  = blockIdx.x;             // 0..255
    const int bh = b >> 3, i8 = b & 7;

    const int tid  = threadIdx.x;
    const int wave = tid >> 6, lane = tid & 63;
    const int q31  = lane & 31, hi = lane >> 5;
    const int qh   = wave & 3, kh = wave >> 2;
    const int qrow = qh * 32 + q31;              // item-local q row 0..127

    const unsigned short* Kbh = Kp + (size_t)bh * S_LEN * DHDIM;
    const unsigned short* Vbh = Vp + (size_t)bh * DHDIM * S_LEN;
    const int sr = tid >> 3, sc = (tid & 7) * 8;   // staging rows 0..63

    #pragma unroll 1
    for (int it = 0; it < 2; ++it) {
        const int qp = it ? i8 : (15 - i8);      // lengths 32-2*i8, then 2*i8+2
        const int k1 = 2 * qp + 2;
        const int gq = qp * 128 + qrow;          // global q row
        const int diag_kt = gq >> 6;             // wave-uniform

        // ---- Q B-fragments, direct from global (pre-scaled bf16 from prep)
        const unsigned short* qsrc = Qp + ((size_t)bh * S_LEN + gq) * DHDIM;
        const bf16x8 bq0 = *(const bf16x8*)(qsrc + hi * 8);
        const bf16x8 bq1 = *(const bf16x8*)(qsrc + 16 + hi * 8);
        const bf16x8 bq2 = *(const bf16x8*)(qsrc + 32 + hi * 8);
        const bf16x8 bq3 = *(const bf16x8*)(qsrc + 48 + hi * 8);

        f32x16 of2[2];
        #pragma unroll
        for (int i = 0; i < 16; i++) { of2[0][i] = 0.f; of2[1][i] = 0.f; }
        float l_p = 0.f;

        __syncthreads();  // prior item's epilogue fs reads done before staging

        // ---- prologue: stage tile 0, prefetch tile 1
        uint4 kr, vr;
        kr = *(const uint4*)(Kbh + (size_t)sr * DHDIM + sc);
        vr = *(const uint4*)(Vbh + (size_t)sr * S_LEN + sc);
        *(uint4*)&ksA[sr][sc]  = kr;
        *(uint4*)&vtsA[sr][sc] = vr;
        if (1 < k1) {
            kr = *(const uint4*)(Kbh + ((size_t)64 + sr) * DHDIM + sc);
            vr = *(const uint4*)(Vbh + (size_t)sr * S_LEN + 64 + sc);
        }

        for (int kt = 0; kt < k1; kt++) {
            __syncthreads();  // buf[kt&1] written; prior reads of other buf done

            if (kt + 1 < k1) {  // write next tile's buffer; prefetch kt+2
                unsigned short (*ks)[LDP]  = ((kt + 1) & 1) ? ksB : ksA;
                unsigned short (*vts)[LDP] = ((kt + 1) & 1) ? vtsB : vtsA;
                *(uint4*)&ks[sr][sc]  = kr;
                *(uint4*)&vts[sr][sc] = vr;
                if (kt + 2 < k1) {
                    kr = *(const uint4*)(Kbh + ((size_t)(kt + 2) * 64 + sr) * DHDIM + sc);
                    vr = *(const uint4*)(Vbh + (size_t)sr * S_LEN + (kt + 2) * 64 + sc);
                }
            }

            if (kt > diag_kt) continue;  // fully-masked tile for this wave

            const unsigned short (*ksc)[LDP] = (kt & 1) ? ksB : ksA;
            const unsigned short (*vtc)[LDP] = (kt & 1) ? vtsB : vtsA;

            // ---- St(kt): quadrant (kh, qh); A = K read once, B = Q in regs
            f32x16 sf;
            #pragma unroll
            for (int i = 0; i < 16; i++) sf[i] = -M2;
            __builtin_amdgcn_s_setprio(1);
            {
                bf16x8 ak = *(const bf16x8*)&ksc[kh * 32 + q31][hi * 8];
                sf = __builtin_amdgcn_mfma_f32_32x32x16_bf16(ak, bq0, sf, 0, 0, 0);
                ak = *(const bf16x8*)&ksc[kh * 32 + q31][16 + hi * 8];
                sf = __builtin_amdgcn_mfma_f32_32x32x16_bf16(ak, bq1, sf, 0, 0, 0);
                ak = *(const bf16x8*)&ksc[kh * 32 + q31][32 + hi * 8];
                sf = __builtin_amdgcn_mfma_f32_32x32x16_bf16(ak, bq2, sf, 0, 0, 0);
                ak = *(const bf16x8*)&ksc[kh * 32 + q31][48 + hi * 8];
                sf = __builtin_amdgcn_mfma_f32_32x32x16_bf16(ak, bq3, sf, 0, 0, 0);
            }
            __builtin_amdgcn_s_setprio(0);

            // ---- softmax numerator -> packed pdw; l accumulates in VALU
            const bool diag = (kt == diag_kt);
            const int qmod = gq & 63;
            unsigned pdw[8];
            #pragma unroll
            for (int g = 0; g < 4; g++) {
                float p[4];
                #pragma unroll
                for (int r2 = 0; r2 < 4; r2++) {
                    float pv = fast_exp2(sf[g * 4 + r2]);
                    if (diag) {
                        const int kl = kh * 32 + 8 * g + 4 * hi + r2;
                        if (kl > qmod) pv = 0.f;
                    }
                    p[r2] = pv;
                    l_p += pv;
                }
                pdw[g * 2]     = packhi(p[0], p[1]);
                pdw[g * 2 + 1] = packhi(p[2], p[3]);
            }

            // ---- PV(kt) in-register: hi-half swap turns D-layout into B-frag
            __builtin_amdgcn_s_setprio(1);
            #pragma unroll
            for (int js = 0; js < 2; js++) {
                const unsigned a0 = pdw[4 * js],     a1 = pdw[4 * js + 1];
                const unsigned b0 = pdw[4 * js + 2], b1 = pdw[4 * js + 3];
                const unsigned pa0 = __shfl_xor(a0, 32), pa1 = __shfl_xor(a1, 32);
                const unsigned pb0 = __shfl_xor(b0, 32), pb1 = __shfl_xor(b1, 32);
                const bf16x8 bp = mk_bf16x8(hi ? pb0 : a0, hi ? pb1 : a1,
                                            hi ? b0 : pa0, hi ? b1 : pa1);
                const int scol = (2 * kh + js) * 16 + hi * 8;
                bf16x8 av = *(const bf16x8*)&vtc[q31][scol];
                of2[0] = __builtin_amdgcn_mfma_f32_32x32x16_bf16(av, bp, of2[0], 0, 0, 0);
                av = *(const bf16x8*)&vtc[32 + q31][scol];
                of2[1] = __builtin_amdgcn_mfma_f32_32x32x16_bf16(av, bp, of2[1], 0, 0, 0);
            }
            __builtin_amdgcn_s_setprio(0);
        }

        // ---- epilogue: l across hi, cross-kh reduction via LDS, write O
        float l2 = l_p + __shfl_xor(l_p, 32);
        __syncthreads();                  // all tiles done; smem reusable
        float* fs = (float*)smem;
        const int base = (qh * 64 + lane) * 36;   // 4x64x36 floats = 36864B
        if (kh == 1) {
            #pragma unroll
            for (int dh = 0; dh < 2; dh++)
                #pragma unroll
                for (int g = 0; g < 4; g++)
                    *(float4*)&fs[base + dh * 16 + g * 4] = make_float4(
                        of2[dh][4 * g], of2[dh][4 * g + 1],
                        of2[dh][4 * g + 2], of2[dh][4 * g + 3]);
            fs[base + 32] = l2;
        }
        __syncthreads();
        if (kh == 0) {
            #pragma unroll
            for (int dh = 0; dh < 2; dh++)
                #pragma unroll
                for (int g = 0; g < 4; g++) {
                    float4 a = *(const float4*)&fs[base + dh * 16 + g * 4];
                    of2[dh][4 * g]     += a.x;
                    of2[dh][4 * g + 1] += a.y;
                    of2[dh][4 * g + 2] += a.z;
                    of2[dh][4 * g + 3] += a.w;
                }
            l2 += fs[base + 32];

            // lane holds O[d = dh*32 + 8g + 4hi + r][q = gq], full K-range
            const float inv = 1.f / l2;
            float* op = O + ((size_t)bh * S_LEN + gq) * DHDIM;
            #pragma unroll
            for (int dh = 0; dh < 2; dh++)
                #pragma unroll
                for (int g = 0; g < 4; g++)
                    *(float4*)(op + dh * 32 + 8 * g + 4 * hi) = make_float4(
                        of2[dh][4 * g] * inv, of2[dh][4 * g + 1] * inv,
                        of2[dh][4 * g + 2] * inv, of2[dh][4 * g + 3] * inv);
        }
    }
}

// ---- fallback kernels (whole-row blocks), used when ws too small
template <bool PRE>
__global__ __launch_bounds__(256) void fattn_kernel(
    const void* __restrict__ Qp, const void* __restrict__ Kp,
    const void* __restrict__ Vp, float* __restrict__ O)
{
    __shared__ unsigned short smem[192 * LDP];
    unsigned short (*ks)[LDP]  = (unsigned short(*)[LDP])smem;
    unsigned short (*vts)[LDP] = (unsigned short(*)[LDP])(smem + 64 * LDP);
    unsigned short (*qs)[LDP]  = (unsigned short(*)[LDP])(smem + 128 * LDP);
    unsigned short (*pst)[LDP] = qs;

    const int id = blockIdx.y * 32 + blockIdx.x;
    const int g  = id >> 8;
    const int r8 = id & 255;
    const int bh = r8 >> 3;
    const int s8 = r8 & 7;
    const int qt = (g == 0) ? 31 - 2 * s8 : (g == 1) ? 2 * s8
                 : (g == 2) ? 30 - 2 * s8 : 2 * s8 + 1;

    const int tid = threadIdx.x;
    const int wave = tid >> 6, lane = tid & 63;
    const int quad = lane >> 4, l16 = lane & 15;

    if constexpr (PRE) {
        const unsigned short* src = (const unsigned short*)Qp
            + ((size_t)bh * S_LEN + qt * 64) * DHDIM;
        for (int c = tid; c < 512; c += 256) {
            int row = c >> 3, c8 = (c & 7) * 8;
            *(uint4*)&qs[row][c8] = *(const uint4*)(src + row * DHDIM + c8);
        }
    } else {
        const float* src = (const float*)Qp + ((size_t)bh * S_LEN + qt * 64) * DHDIM;
        for (int c = tid; c < 512; c += 256) {
            int row = c >> 3, c8 = (c & 7) * 8;
            float f[8]; ld8(src + row * DHDIM + c8, f);
            *(uint4*)&qs[row][c8] = pack8(f, QSCALE);
        }
    }
    __syncthreads();

    const int prow = wave * 16 + l16;
    const bf16x8 bq0 = *(const bf16x8*)&qs[prow][quad * 8];
    const bf16x8 bq1 = *(const bf16x8*)&qs[prow][32 + quad * 8];

    float l_p = 0.f;
    f32x4 of[4];
    #pragma unroll
    for (int n = 0; n < 4; n++) of[n] = (f32x4){0.f, 0.f, 0.f, 0.f};

    for (int kt = 0; kt <= qt; kt++) {
        __syncthreads();
        if constexpr (PRE) {
            const unsigned short* ksrc = (const unsigned short*)Kp
                + ((size_t)bh * S_LEN + kt * 64) * DHDIM;
            const unsigned short* vsrc = (const unsigned short*)Vp
                + (size_t)bh * DHDIM * S_LEN + kt * 64;
            for (int c = tid; c < 512; c += 256) {
                int row = c >> 3, c8 = (c & 7) * 8;
                *(uint4*)&ks[row][c8]  = *(const uint4*)(ksrc + row * DHDIM + c8);
                *(uint4*)&vts[row][c8] = *(const uint4*)(vsrc + (size_t)row * S_LEN + c8);
            }
        } else {
            const float* ksrc = (const float*)Kp + ((size_t)bh * S_LEN + kt * 64) * DHDIM;
            const float* vsrc = (const float*)Vp + ((size_t)bh * S_LEN + kt * 64) * DHDIM;
            for (int c = tid; c < 512; c += 256) {
                int row = c >> 3, c8 = (c & 7) * 8;
                float f[8];
                ld8(ksrc + row * DHDIM + c8, f);
                *(uint4*)&ks[row][c8] = pack8(f, 1.0f);
                ld8(vsrc + row * DHDIM + c8, f);
                #pragma unroll
                for (int j = 0; j < 8; j++) vts[c8 + j][row] = f2bf(f[j]);
            }
        }
        __syncthreads();

        f32x4 sf[4];
        #pragma unroll
        for (int n = 0; n < 4; n++) {
            bf16x8 ak0 = *(const bf16x8*)&ks[n * 16 + l16][quad * 8];
            bf16x8 ak1 = *(const bf16x8*)&ks[n * 16 + l16][32 + quad * 8];
            sf[n] = (f32x4){-M2, -M2, -M2, -M2};
            sf[n] = __builtin_amdgcn_mfma_f32_16x16x32_bf16(ak0, bq0, sf[n], 0, 0, 0);
            sf[n] = __builtin_amdgcn_mfma_f32_16x16x32_bf16(ak1, bq1, sf[n], 0, 0, 0);
        }

        const bool diag = (kt == qt);
        #pragma unroll
        for (int n = 0; n < 4; n++) {
            float p[4];
            #pragma unroll
            for (int r = 0; r < 4; r++) {
                p[r] = fast_exp2(sf[n][r]);
                if (diag && (n * 16 + quad * 4 + r > prow)) p[r] = 0.f;
                l_p += p[r];
            }
            uint2 dw;
            dw.x = packhi(p[0], p[1]);
            dw.y = packhi(p[2], p[3]);
            *(uint2*)&pst[prow][n * 16 + quad * 4] = dw;
        }
        asm volatile("s_waitcnt lgkmcnt(0)" ::: "memory");

        bf16x8 bp0 = *(const bf16x8*)&pst[prow][quad * 8];
        bf16x8 bp1 = *(const bf16x8*)&pst[prow][32 + quad * 8];
        #pragma unroll
        for (int n = 0; n < 4; n++) {
            bf16x8 av0 = *(const bf16x8*)&vts[n * 16 + l16][quad * 8];
            bf16x8 av1 = *(const bf16x8*)&vts[n * 16 + l16][32 + quad * 8];
            of[n] = __builtin_amdgcn_mfma_f32_16x16x32_bf16(av0, bp0, of[n], 0, 0, 0);
            of[n] = __builtin_amdgcn_mfma_f32_16x16x32_bf16(av1, bp1, of[n], 0, 0, 0);
        }
    }

    l_p += __shfl_xor(l_p, 16);
    l_p += __shfl_xor(l_p, 32);
    const float inv = 1.f / l_p;
    float* op = O + ((size_t)bh * S_LEN + qt * 64 + prow) * DHDIM;
    #pragma unroll
    for (int n = 0; n < 4; n++)
        *(float4*)(op + n * 16 + quad * 4) = make_float4(
            of[n][0] * inv, of[n][1] * inv, of[n][2] * inv, of[n][3] * inv);
}

extern "C" void kernel_launch(void* const* d_in, const int* in_sizes, int n_in,
                              void* d_out, int out_size, void* d_ws, size_t ws_size,
                              hipStream_t stream) {
    const float* Q = (const float*)d_in[0];
    const float* K = (const float*)d_in[1];
    const float* V = (const float*)d_in[2];
    // d_in[3] = causal mask: analytic, not read.
    float* O = (float*)d_out;
    const size_t N = (size_t)NHEADS * S_LEN * DHDIM;      // 4,194,304 elems
    const size_t prepB  = 3 * N * sizeof(unsigned short); // 25.2 MB

    if (d_ws && ws_size >= prepB) {
        unsigned short* qb  = (unsigned short*)d_ws;
        unsigned short* kb  = qb + N;
        unsigned short* vtb = kb + N;
        prep<<<dim3(S_LEN / 64, NHEADS), 256, 0, stream>>>(Q, K, V, qb, kb, vtb);
        fattn_single<<<dim3(256), 512, 0, stream>>>(qb, kb, vtb, O);
    } else {
        fattn_kernel<false><<<dim3(32, 32), 256, 0, stream>>>(Q, K, V, O);
    }
}